// Round 10
// baseline (2093.873 us; speedup 1.0000x reference)
//
#include <hip/hip_runtime.h>
#include <stdint.h>

#define B_SZ   256
#define T_SZ   1000
#define N_IN   128
#define UNITS  512
#define CH     32        // rows per staged chunk (2 KB each)

// dynamic LDS layout (bytes):
//   [0, 131072)   float stage[2][CH][512]   (double-buffered row window)
//   [131072, ...) int   list[544]           (512 + 32 pad slots of idx 512)
//                 int   s_cnt[8]; int s_total
#define SMEM_BYTES (2 * CH * UNITS * 4 + 544 * 4 + 8 * 4 + 16)

// ---------------------------------------------------------------------------
// Phase 0: Wz[513][512]: W_rec with diag zeroed + all-zero row 512. Pad-slot
// (idx 512) and diagonal reads give exact +0.0f -> unconditional add chain,
// bit-identical to the predicated r1 chain (proven r5..r9, absmax 0.0).
// ---------------------------------------------------------------------------
__global__ __launch_bounds__(512) void wz_prep(const float* __restrict__ Wr,
                                               float* __restrict__ Wz) {
    const int c = threadIdx.x, r = blockIdx.x;
    Wz[(size_t)r * UNITS + c] =
        (r >= UNITS || r == c) ? 0.0f : Wr[(size_t)r * UNITS + c];
}

// ---------------------------------------------------------------------------
// Phase 1: C[M,512] = X[M,128] @ W[128,512]  (unchanged, ~fp32 roofline)
// ---------------------------------------------------------------------------
__global__ __launch_bounds__(256) void gemm_in(const float* __restrict__ X,
                                               const float* __restrict__ W,
                                               float* __restrict__ C) {
    __shared__ __align__(16) float As[32][128];
    __shared__ __align__(16) float Bs[32][128];

    const int tid = threadIdx.x;
    const int ntile = blockIdx.x & 3;
    const int mtile = blockIdx.x >> 2;
    const int m0 = mtile * 128, n0 = ntile * 128;
    const int tm  = (tid >> 4) * 8;
    const int tn4 = (tid & 15) * 4;

    float acc[8][8];
#pragma unroll
    for (int i = 0; i < 8; ++i)
#pragma unroll
        for (int j = 0; j < 8; ++j) acc[i][j] = 0.0f;

    for (int k0 = 0; k0 < 128; k0 += 32) {
        __syncthreads();
#pragma unroll
        for (int r = 0; r < 4; ++r) {
            int li  = r * 256 + tid;
            int row = li >> 3;
            int ch  = li & 7;
            float4 a = *(const float4*)&X[(size_t)(m0 + row) * 128 + k0 + ch * 4];
            As[ch * 4 + 0][row] = a.x;
            As[ch * 4 + 1][row] = a.y;
            As[ch * 4 + 2][row] = a.z;
            As[ch * 4 + 3][row] = a.w;
        }
#pragma unroll
        for (int r = 0; r < 4; ++r) {
            int li = r * 256 + tid;
            int kk = li >> 5;
            int n4 = li & 31;
            *(float4*)&Bs[kk][n4 * 4] =
                *(const float4*)&W[(size_t)(k0 + kk) * 512 + n0 + n4 * 4];
        }
        __syncthreads();

#pragma unroll 8
        for (int k = 0; k < 32; ++k) {
            float4 a0 = *(const float4*)&As[k][tm];
            float4 a1 = *(const float4*)&As[k][tm + 4];
            float4 b0 = *(const float4*)&Bs[k][tn4];
            float4 b1 = *(const float4*)&Bs[k][tn4 + 64];
            const float av[8] = {a0.x, a0.y, a0.z, a0.w, a1.x, a1.y, a1.z, a1.w};
            const float bv[8] = {b0.x, b0.y, b0.z, b0.w, b1.x, b1.y, b1.z, b1.w};
#pragma unroll
            for (int i = 0; i < 8; ++i)
#pragma unroll
                for (int j = 0; j < 8; ++j)
                    acc[i][j] = fmaf(av[i], bv[j], acc[i][j]);
        }
    }

#pragma unroll
    for (int i = 0; i < 8; ++i) {
        size_t row = (size_t)(m0 + tm + i) * 512;
        float4 c0 = make_float4(acc[i][0], acc[i][1], acc[i][2], acc[i][3]);
        float4 c1 = make_float4(acc[i][4], acc[i][5], acc[i][6], acc[i][7]);
        *(float4*)&C[row + n0 + tn4]      = c0;
        *(float4*)&C[row + n0 + 64 + tn4] = c1;
    }
}

// ---------------------------------------------------------------------------
// Phase 2: ALIF scan. One WG per batch (grid 256, 512 thr), thread u owns
// unit u. The per-thread gather (latency-bound at 53% of the demonstrated
// 61 B/cy per-CU floor, r6) is replaced by cooperative global_load_lds
// streaming: active rows staged into a double-buffered LDS window (CH=32
// rows/chunk; wave w stages 4 rows/chunk via 2x width-16 global_load_lds),
// then the ascending add chain reads LDS (consecutive-u, conflict-free).
// Staging of chunk c+1 overlaps the adds of chunk c; __syncthreads' vmcnt
// drain is the intended completion wait (m97 pattern).
// Numerics: slots ascend in j; pads (idx 512) stage the Wz zero row ->
// unconditional __fadd_rn chain bit-identical to all passing rounds.
// ---------------------------------------------------------------------------
__global__ __launch_bounds__(512, 2) void alif_scan(const float* __restrict__ Wz,
                                                    float* __restrict__ IO) {
    extern __shared__ __align__(16) float smem[];
    float* stage   = smem;                             // [2][CH][512]
    int*   lst     = (int*)(smem + 2 * CH * UNITS);    // [544]
    int*   s_cnt   = lst + 544;                        // [8]
    int*   s_total = s_cnt + 8;                        // [1]

    const int b = blockIdx.x;
    const int u = threadIdx.x;
    const int w = u >> 6;
    const int lane = u & 63;

    const float DECAY   = 0.95122942450071400910f;   // exp(-1/20)
    const float OMD     = 1.0f - DECAY;
    const float DECAY_B = 0.99501247919268232342f;   // exp(-1/200)
    const float OMDB    = 1.0f - DECAY_B;

    float v = 0.0f, ad = 0.0f, z = 0.0f;

    float* io = IO + (size_t)b * (T_SZ * UNITS) + u;

    // init: whole list = pad idx 512; totals zero
    lst[u] = UNITS;
    if (u < 32) lst[UNITS + u] = UNITS;
    if (u < 8) s_cnt[u] = 0;
    if (u == 0) *s_total = 0;
    __syncthreads();

    float i_cur = io[0];

    // wave w stages slots [chunk*CH + w*4, +4): 2 width-16 async loads each
    auto STAGE = [&](int chunk, int buf) {
        float* dstbase = stage + buf * (CH * UNITS);
#pragma unroll
        for (int i = 0; i < 4; ++i) {
            const int sl = w * 4 + i;                 // slot within chunk
            const int s  = chunk * CH + sl;
            const int j  = lst[s];                    // uniform within wave
            const float* g = Wz + (size_t)j * UNITS + lane * 4;
            float* d = dstbase + sl * UNITS;
            __builtin_amdgcn_global_load_lds(
                (const __attribute__((address_space(1))) void*)g,
                (__attribute__((address_space(3))) void*)d, 16, 0, 0);
            __builtin_amdgcn_global_load_lds(
                (const __attribute__((address_space(1))) void*)(g + 256),
                (__attribute__((address_space(3))) void*)(d + 256), 16, 0, 0);
        }
    };

    for (int t = 0; t < T_SZ; ++t) {
        // prefetch next step's input current
        float i_next = io[(t + 1 < T_SZ ? t + 1 : t) * UNITS];

        const int cnt = *s_total;
        const int nch = (cnt + CH - 1) >> 5;          // chunks this step
        float acc = 0.0f;

        if (nch > 0) {
            STAGE(0, 0);
            for (int c = 0; c < nch; ++c) {
                __syncthreads();                      // chunk c staged (vmcnt drain)
                if (c + 1 < nch) STAGE(c + 1, (c + 1) & 1);
                const float* bs = stage + (c & 1) * (CH * UNITS) + u;
#pragma unroll
                for (int k = 0; k < CH; ++k)
                    acc = __fadd_rn(acc, bs[(size_t)k * UNITS]);
            }
        }

        // ---- elementwise state update — exact reference op order ----
        float newb = __fadd_rn(__fmul_rn(DECAY_B, ad), __fmul_rn(OMDB, z));
        float thr  = __fadd_rn(0.01f, __fmul_rn(newb, 1.6f));
        float it   = __fadd_rn(__fadd_rn(i_cur, acc), 0.0f);       // + ADD_CUR
        float ires = __fmul_rn(__fmul_rn(z, thr), 1.0f);           // * DT
        float newv = __fsub_rn(
            __fadd_rn(__fmul_rn(DECAY, v), __fmul_rn(OMD, it)), ires);
        float zn = (newv > thr) ? 1.0f : 0.0f;      // refractory is a no-op

        io[t * UNITS] = zn;
        v = newv; ad = newb; z = zn; i_cur = i_next;

        // ---- rebuild contiguous ascending active list (r1 scheme) ----
        unsigned long long m = __ballot(zn > 0.0f);
        if (lane == 0) s_cnt[w] = __popcll(m);
        __syncthreads();   // [A] all reads of old list done; counts visible

        int base = 0, total = 0;
#pragma unroll
        for (int i = 0; i < 8; ++i) {
            int c = s_cnt[i];
            total += c;
            if (i < w) base += c;
        }
        if (zn > 0.0f) {
            int pos = base + __popcll(m & ((1ull << lane) - 1ull));
            lst[pos] = u;
        }
        if (u == 0) *s_total = total;
        if (u < 32) lst[total + u] = UNITS;          // pad idx -> zero row
        __syncthreads();   // [C] list ready
    }
}

extern "C" void kernel_launch(void* const* d_in, const int* in_sizes, int n_in,
                              void* d_out, int out_size, void* d_ws, size_t ws_size,
                              hipStream_t stream) {
    (void)in_sizes; (void)n_in; (void)out_size; (void)ws_size;
    const float* x     = (const float*)d_in[0];   // [B,T,128]
    const float* W_in  = (const float*)d_in[1];   // [128,512]
    const float* W_rec = (const float*)d_in[2];   // [512,512]
    float* out = (float*)d_out;                   // [B,T,512]
    float* Wz  = (float*)d_ws;                    // [513][512] zero-diag copy

    wz_prep<<<dim3(UNITS + 1), dim3(UNITS), 0, stream>>>(W_rec, Wz);
    gemm_in<<<dim3((B_SZ * T_SZ / 128) * (UNITS / 128)), dim3(256), 0, stream>>>(
        x, W_in, out);

    hipFuncSetAttribute((const void*)alif_scan,
                        hipFuncAttributeMaxDynamicSharedMemorySize, SMEM_BYTES);
    alif_scan<<<dim3(B_SZ), dim3(512), SMEM_BYTES, stream>>>(Wz, out);
}